// Round 17
// baseline (236.318 us; speedup 1.0000x reference)
//
#include <hip/hip_runtime.h>
#include <hip/hip_bf16.h>

#define SEQ 1024
#define NH  16

typedef __attribute__((ext_vector_type(8))) short short8;
typedef __attribute__((ext_vector_type(4))) float floatx4;
typedef __attribute__((ext_vector_type(4))) unsigned short ushortx4;

// async global->LDS, 16B per lane; LDS dest = wave-uniform base + lane*16
#define GLDS16(gp, lp) __builtin_amdgcn_global_load_lds( \
    (const __attribute__((address_space(1))) void*)(gp), \
    (__attribute__((address_space(3))) void*)(lp), 16, 0, 0)

// fp32 -> bf16 RNE via native HW convert (compiler pairs into v_cvt_pk_bf16_f32)
__device__ __forceinline__ unsigned short f2b(float f) {
    union { __hip_bfloat16 h; unsigned short u; } v;
    v.h = __float2bfloat16(f);
    return v.u;
}
__device__ __forceinline__ float b2f(unsigned short h) {
    union { unsigned u; float f; } v; v.u = ((unsigned)h) << 16;
    return v.f;
}

// swizzled addr helper (element offsets in a 64-wide bf16 tile: 8 chunks of 16B/row)
#define TADDR(base, row, ch) ((base) + ((row) << 6) + ((((ch) ^ ((row) & 7))) << 3))

// ---------------- k0: fp32 -> bf16 casts ----------------
__global__ void cast_kernel(const float* __restrict__ hs, const float* __restrict__ W,
                            const float* __restrict__ E,
                            unsigned short* __restrict__ hsb,
                            unsigned short* __restrict__ Wb,
                            unsigned short* __restrict__ Eb)
{
    const int QH = 1048576, QW = 786432, QE = 32752;   // quads
    const int NT = QH + QW + QE;
    for (int q = blockIdx.x * 256 + threadIdx.x; q < NT; q += gridDim.x * 256) {
        const float* src; unsigned short* dst; int off;
        if (q < QH)           { src = hs; dst = hsb; off = q; }
        else if (q < QH + QW) { src = W;  dst = Wb;  off = q - QH; }
        else                  { src = E;  dst = Eb;  off = q - QH - QW; }
        const float4 v = *(const float4*)(src + (size_t)off * 4);
        ushortx4 o; o[0] = f2b(v.x); o[1] = f2b(v.y); o[2] = f2b(v.z); o[3] = f2b(v.w);
        *(ushortx4*)(dst + (size_t)off * 4) = o;
    }
}

// ---------------- k1: QKV projection — 2-phase K-loop + LDS-staged coalesced epilogue ----
__global__ __launch_bounds__(256, 3) void qkv_gemm(
    const unsigned short* __restrict__ Ab, const unsigned short* __restrict__ Bb,
    const float* __restrict__ bias,
    unsigned short* __restrict__ Qb, unsigned short* __restrict__ Kb,
    unsigned short* __restrict__ Vt)
{
    __shared__ unsigned short sm[16384];
    const int t = threadIdx.x, w = t >> 6;
    const int ln = t & 15, g = (t >> 4) & 3;
    const int wm = w >> 1, wn = w & 1;
    // XCD-chunked swizzle: 768 wgs = 8 XCDs x 96
    const int bid = blockIdx.x + blockIdx.y * 24;
    const int swzid = (bid & 7) * 96 + (bid >> 3);
    const int m0 = (swzid / 24) << 7, o0 = (swzid % 24) << 7;

    floatx4 acc[4][4];
#pragma unroll
    for (int i = 0; i < 4; ++i)
#pragma unroll
        for (int j = 0; j < 4; ++j) acc[i][j] = (floatx4){0.f, 0.f, 0.f, 0.f};

    auto stage = [&](int kb, int buf) {
        const int base = buf << 14;              // bytes
#pragma unroll
        for (int p = 0; p < 2; ++p) {
            const int idx = (p << 8) + t;
            const int row = idx >> 2;
            const int c = (idx & 3) ^ ((row ^ (row >> 2)) & 3);
            GLDS16(Ab + (size_t)(m0 + row) * 1024 + kb + (c << 3),
                   (char*)sm + base + (p << 12) + (w << 10));
            GLDS16(Bb + (size_t)(o0 + row) * 1024 + kb + (c << 3),
                   (char*)sm + base + 8192 + (p << 12) + (w << 10));
        }
    };

    stage(0, 0);
    __syncthreads();
    int buf = 0;
    for (int kb = 0; kb < 1024; kb += 32) {
        if (kb + 32 < 1024) stage(kb + 32, buf ^ 1);   // issue next-tile loads early
        const int be = buf << 13;                      // elems
        short8 af[4], bf_[4];
#pragma unroll
        for (int i = 0; i < 4; ++i) {
            const int r = (wm << 6) + (i << 4) + ln;
            af[i] = *(const short8*)&sm[be + (r << 5) + ((g ^ ((r ^ (r >> 2)) & 3)) << 3)];
        }
#pragma unroll
        for (int j = 0; j < 4; ++j) {
            const int r = (wn << 6) + (j << 4) + ln;
            bf_[j] = *(const short8*)&sm[be + 4096 + (r << 5) + ((g ^ ((r ^ (r >> 2)) & 3)) << 3)];
        }
#pragma unroll
        for (int i = 0; i < 4; ++i)
#pragma unroll
            for (int j = 0; j < 4; ++j)
                acc[i][j] = __builtin_amdgcn_mfma_f32_16x16x32_bf16(af[i], bf_[j], acc[i][j], 0, 0, 0);
        __syncthreads();                               // drains GLDS + syncs reads
        buf ^= 1;
    }

    const int which = o0 >> 10;     // 0=Q 1=K 2=V (block-uniform)
    float bj[4];
#pragma unroll
    for (int j = 0; j < 4; ++j) bj[j] = bias[o0 + (wn << 6) + (j << 4) + ln];
    const int b0 = m0 >> 10;        // tile stays within one batch (128 | 1024)

    if (which == 2) {
        // V: LDS transposed tile, elem(oi,mi) = oi*128 + ((mi>>3)^(oi&15))*8 + (mi&7)
#pragma unroll
        for (int i = 0; i < 4; ++i)
#pragma unroll
            for (int j = 0; j < 4; ++j) {
                const int oi = (wn << 6) + (j << 4) + ln;
                const int sb = oi & 15;
#pragma unroll
                for (int q = 0; q < 4; ++q) {
                    const int mi = (wm << 6) + (i << 4) + (g << 2) + q;
                    sm[(oi << 7) + ((((mi >> 3) ^ sb)) << 3) + (mi & 7)] =
                        f2b(acc[i][j][q] + bj[j]);
                }
            }
        __syncthreads();
#pragma unroll
        for (int it = 0; it < 8; ++it) {
            const int c = (it << 8) + t;
            const int oi = c >> 4, mi0 = (c & 15) << 3;
            const short8 v = *(const short8*)&sm[(oi << 7) + ((((mi0 >> 3) ^ (oi & 15))) << 3)];
            const int hh = ((o0 >> 6) + (oi >> 6)) & 15;
            const int d = oi & 63;
            const int s0 = (m0 & 1023) + mi0;
            *(short8*)(Vt + (((size_t)((b0 << 4) + hh)) << 16) + (d << 10) + s0) = v;
        }
    } else {
        unsigned short* dst = which ? Kb : Qb;
        const float sc = which ? 1.0f : 0.125f;   // fold 1/sqrt(64) into Q
        // Q/K: LDS row-major tile, elem(mi,oi) = mi*128 + oi
#pragma unroll
        for (int i = 0; i < 4; ++i)
#pragma unroll
            for (int j = 0; j < 4; ++j) {
                const int oi = (wn << 6) + (j << 4) + ln;
#pragma unroll
                for (int q = 0; q < 4; ++q) {
                    const int mi = (wm << 6) + (i << 4) + (g << 2) + q;
                    sm[(mi << 7) + oi] = f2b((acc[i][j][q] + bj[j]) * sc);
                }
            }
        __syncthreads();
#pragma unroll
        for (int it = 0; it < 8; ++it) {
            const int c = (it << 8) + t;
            const int mi = c >> 4, oi0 = (c & 15) << 3;
            const short8 v = *(const short8*)&sm[(mi << 7) + oi0];
            const int s = (m0 & 1023) + mi;
            const int hh = ((o0 >> 6) + (oi0 >> 6)) & 15;
            const int d0 = oi0 & 63;
            *(short8*)(dst + (((size_t)((b0 << 4) + hh)) << 16) + (s << 6) + d0) = v;
        }
    }
}

// ---------------- k2: n-way split-K flash attention (R11-exact inner loop) ----------------
// grid = 1024*np; job u -> (piece = u>>10, rest = u&1023 -> bh,l0).
// piece covers tiles [piece*16/np, (piece+1)*16/np) of the 16 key-tiles.
// Writes UNNORMALIZED partials: O(f32) + per-row (m,l); piece 0 writes into out.
// LDS layout identical to R11/R16 (50 KiB -> 3 blocks/CU, 768 residency slots).
// np=3 -> 3072 jobs = 768 slots x 4.0 exactly (no packing remainder).
__global__ __launch_bounds__(256, 3) void attn_split(
    const unsigned short* __restrict__ Qb, const unsigned short* __restrict__ Kb,
    const unsigned short* __restrict__ Vt, const unsigned short* __restrict__ Eb,
    const float* __restrict__ mask,
    float* __restrict__ pO0, float* __restrict__ pOx,
    float* __restrict__ mArr, float* __restrict__ lArr, int np)
{
    __shared__ __align__(16) unsigned short sm[25600];
    const int t = threadIdx.x, w = t >> 6;
    const int wu = __builtin_amdgcn_readfirstlane(w);   // wave-uniform in SGPR
    const int ln = t & 15, g = (t >> 4) & 3;
    const int bid = blockIdx.x;
    const int chunk = gridDim.x >> 3;                   // XCD-bijective (grid % 8 == 0)
    const int u = (bid & 7) * chunk + (bid >> 3);
    const int piece = u >> 10;
    const int rest = u & 1023;
    const int bh = rest >> 4;
    const int l0 = (rest & 15) << 6;
    const int b = bh >> 4, h = bh & 15;
    const size_t hb = (size_t)bh << 16;
    const int x0 = (w << 4) + (g << 2);          // thread's base l-row
    const int r0beg = ((piece * 16) / np) << 6;
    const int r0end = (((piece + 1) * 16) / np) << 6;

    // Q fragments direct from global (pre-scaled; read once, L2-hot)
    const int qr = (w << 4) + ln;
    const short8 qa0 = *(const short8*)(Qb + hb + ((size_t)(l0 + qr) << 6) + (g << 3));
    const short8 qa1 = *(const short8*)(Qb + hb + ((size_t)(l0 + qr) << 6) + 32 + (g << 3));

    floatx4 O[4];
    float mr[4], lr[4];
#pragma unroll
    for (int dt = 0; dt < 4; ++dt) O[dt] = (floatx4){0.f, 0.f, 0.f, 0.f};
#pragma unroll
    for (int q = 0; q < 4; ++q) { mr[q] = -1e30f; lr[q] = 0.f; }

    for (int r0 = r0beg; r0 < r0end; r0 += 64) {
        __syncthreads();                         // A: prev PV/V reads done
#pragma unroll
        for (int p = 0; p < 2; ++p) {            // stage K at elems [0,4096)
            const int idx = (p << 8) + t;
            const int row = idx >> 3;
            const int c = (idx & 7) ^ (row & 7);
            GLDS16(Kb + hb + ((size_t)(r0 + row) << 6) + (c << 3),
                   (char*)sm + (p << 12) + (w << 10));
        }
        const int j0 = l0 - r0 + 960;            // E band start, in [0,1920]
#pragma unroll
        for (int p = 0; p < 4; ++p) {            // stage E band (128 rows) at elems [4096,12288)
            const int idx = (p << 8) + t;
            const int row = idx >> 3;
            const int c = (idx & 7) ^ (row & 7);
            GLDS16(Eb + ((size_t)(j0 + row) << 6) + (c << 3),
                   (char*)sm + 8192 + (p << 12) + (w << 10));
        }
        __syncthreads();                         // B: staging visible
        short8 kf[4][2];
#pragma unroll
        for (int j = 0; j < 4; ++j) {
            const int kr = (j << 4) + ln;
            kf[j][0] = *(const short8*)&sm[TADDR(0, kr, g)];
            kf[j][1] = *(const short8*)&sm[TADDR(0, kr, 4 + g)];
        }
        const int wr = (w << 4) + ln;            // W A-fragment (this wave's K rows)
        const short8 ka0 = *(const short8*)&sm[TADDR(0, wr, g)];
        const short8 ka1 = *(const short8*)&sm[TADDR(0, wr, 4 + g)];

        floatx4 S[4];
#pragma unroll
        for (int j = 0; j < 4; ++j) {
            floatx4 z = (floatx4){0.f, 0.f, 0.f, 0.f};
            z = __builtin_amdgcn_mfma_f32_16x16x32_bf16(qa0, kf[j][0], z, 0, 0, 0);
            S[j] = __builtin_amdgcn_mfma_f32_16x16x32_bf16(qa1, kf[j][1], z, 0, 0, 0);
        }
        // band GEMMs, pruned per wave; outputs written pre-sheared
#pragma unroll
        for (int dt = 0; dt < 8; ++dt) {
            const bool doU = (dt >= wu) && (dt <= wu + 4);
            const bool doW = (dt >= 3 - wu) && (dt <= 7 - wu);
            if (!doU && !doW) continue;
            const int er = (dt << 4) + ln;
            const short8 e0 = *(const short8*)&sm[TADDR(4096, er, g)];
            const short8 e1 = *(const short8*)&sm[TADDR(4096, er, 4 + g)];
            if (doU) {
                floatx4 z = (floatx4){0.f, 0.f, 0.f, 0.f};
                z = __builtin_amdgcn_mfma_f32_16x16x32_bf16(qa0, e0, z, 0, 0, 0);
                const floatx4 U = __builtin_amdgcn_mfma_f32_16x16x32_bf16(qa1, e1, z, 0, 0, 0);
                // cell (rr = ll-br+63, ll), ll = x0+q, br = 16dt+ln; rr+16 in [0,95]
                int a = 12288 + (x0 - (dt << 4) - ln + 79) * 72 + x0;
#pragma unroll
                for (int q = 0; q < 4; ++q) { sm[a] = f2b(U[q]); a += 73; }
            }
            if (doW) {
                floatx4 z2 = (floatx4){0.f, 0.f, 0.f, 0.f};
                z2 = __builtin_amdgcn_mfma_f32_16x16x32_bf16(ka0, e0, z2, 0, 0, 0);
                const floatx4 Wv = __builtin_amdgcn_mfma_f32_16x16x32_bf16(ka1, e1, z2, 0, 0, 0);
                // cell (rW = x0+q, ll+16 = 16dt+ln+x0+q-47), ll+16 in [1,95]
                int a = 19200 + x0 * 101 + (dt << 4) + ln - 47;
#pragma unroll
                for (int q = 0; q < 4; ++q) { sm[a] = f2b(Wv[q] * 0.125f); a += 101; }
            }
        }
        __syncthreads();                         // C: U'/W' visible; E dead
#pragma unroll
        for (int p = 0; p < 2; ++p) {            // stage V (transposed) over dead E
            const int idx = (p << 8) + t;
            const int row = idx >> 3;            // = d
            const int c = (idx & 7) ^ (row & 7);
            GLDS16(Vt + hb + ((size_t)row << 10) + r0 + (c << 3),
                   (char*)sm + 8192 + (p << 12) + (w << 10));
        }
        // assemble scores: vector b64 reads + global mask (L2-hot)
        float Pw[4][4];
#pragma unroll
        for (int j = 0; j < 4; ++j) {
            const int rr = (j << 4) + ln;
            const float mk = mask[(b << 10) + r0 + rr];
            const ushortx4 u4 = *(const ushortx4*)&sm[12288 + (rr + 16) * 72 + x0];
            const ushortx4 w4 = *(const ushortx4*)&sm[19200 + rr * 100 + 16 + x0];
#pragma unroll
            for (int q = 0; q < 4; ++q)
                S[j][q] += b2f(u4[q]) + b2f(w4[q]) + mk;
        }
#pragma unroll
        for (int q = 0; q < 4; ++q) {
            float tm = fmaxf(fmaxf(S[0][q], S[1][q]), fmaxf(S[2][q], S[3][q]));
            tm = fmaxf(tm, __shfl_xor(tm, 1));
            tm = fmaxf(tm, __shfl_xor(tm, 2));
            tm = fmaxf(tm, __shfl_xor(tm, 4));
            tm = fmaxf(tm, __shfl_xor(tm, 8));
            const float mnew = fmaxf(mr[q], tm);
            const float al = __expf(mr[q] - mnew);
            float sum = 0.f;
#pragma unroll
            for (int j = 0; j < 4; ++j) {
                const float p = __expf(S[j][q] - mnew);
                Pw[j][q] = p; sum += p;
            }
            sum += __shfl_xor(sum, 1);
            sum += __shfl_xor(sum, 2);
            sum += __shfl_xor(sum, 4);
            sum += __shfl_xor(sum, 8);
            lr[q] = lr[q] * al + sum;
            mr[q] = mnew;
#pragma unroll
            for (int dt = 0; dt < 4; ++dt) O[dt][q] *= al;
        }
        // write P (bf16) into [l][r] swizzled tile at elem 8192
#pragma unroll
        for (int j = 0; j < 4; ++j) {
            const int rr = (j << 4) + ln;
#pragma unroll
            for (int q = 0; q < 4; ++q) {
                const int l = x0 + q;
                sm[8192 + (l << 6) + ((((rr >> 3) ^ (l & 7)) << 3)) + (rr & 7)] = f2b(Pw[j][q]);
            }
        }
        __syncthreads();                         // D: P + V visible
        const int pr = (w << 4) + ln;
        const short8 pa0 = *(const short8*)&sm[TADDR(8192, pr, g)];
        const short8 pa1 = *(const short8*)&sm[TADDR(8192, pr, 4 + g)];
#pragma unroll
        for (int dt = 0; dt < 4; ++dt) {
            const int vr = (dt << 4) + ln;       // = d row of V^T tile
            const short8 v0 = *(const short8*)&sm[TADDR(4096, vr, g)];
            const short8 v1 = *(const short8*)&sm[TADDR(4096, vr, 4 + g)];
            O[dt] = __builtin_amdgcn_mfma_f32_16x16x32_bf16(pa0, v0, O[dt], 0, 0, 0);
            O[dt] = __builtin_amdgcn_mfma_f32_16x16x32_bf16(pa1, v1, O[dt], 0, 0, 0);
        }
    }
    // write UNNORMALIZED partial O + per-row (m, l)
    float* pDst = piece ? (pOx + (size_t)(piece - 1) * 4194304) : pO0;
    float* mDst = mArr + (size_t)piece * 65536;
    float* lDst = lArr + (size_t)piece * 65536;
#pragma unroll
    for (int dt = 0; dt < 4; ++dt)
#pragma unroll
        for (int q = 0; q < 4; ++q) {
            const int l = x0 + q;
            pDst[((size_t)b << 20) + ((size_t)(l0 + l) << 10) + (h << 6) + (dt << 4) + ln]
                = O[dt][q];
        }
    if (ln == 0) {
        const int rowbase = (bh << 10) + l0 + x0;
#pragma unroll
        for (int q = 0; q < 4; ++q) { mDst[rowbase + q] = mr[q]; lDst[rowbase + q] = lr[q]; }
    }
}

// ---------------- k3: merge the np split-K pieces ----------------
__global__ void merge_kernel(const float* __restrict__ pO0, const float* __restrict__ pOx,
                             const float* __restrict__ mArr, const float* __restrict__ lArr,
                             float* __restrict__ outp, int np)
{
    const int idx = blockIdx.x * 256 + threadIdx.x;      // 1,048,576 threads
    const int rowg = idx >> 4, d4 = (idx & 15) << 2;
    const int b = rowg >> 14, h = (rowg >> 10) & 15, l = rowg & 1023;
    const size_t off = ((size_t)b << 20) + ((size_t)l << 10) + (h << 6) + d4;
    float mm = -1e30f;
    for (int p = 0; p < np; ++p) mm = fmaxf(mm, mArr[p * 65536 + rowg]);
    float denom = 0.f;
    float4 acc = {0.f, 0.f, 0.f, 0.f};
    for (int p = 0; p < np; ++p) {
        const float a = __expf(mArr[p * 65536 + rowg] - mm);
        denom += a * lArr[p * 65536 + rowg];
        const float* src = p ? (pOx + (size_t)(p - 1) * 4194304) : pO0;
        const float4 o = *(const float4*)(src + off);
        acc.x += a * o.x; acc.y += a * o.y; acc.z += a * o.z; acc.w += a * o.w;
    }
    const float inv = 1.f / denom;
    float4 r; r.x = acc.x * inv; r.y = acc.y * inv; r.z = acc.z * inv; r.w = acc.w * inv;
    *(float4*)(outp + off) = r;
}

extern "C" void kernel_launch(void* const* d_in, const int* in_sizes, int n_in,
                              void* d_out, int out_size, void* d_ws, size_t ws_size,
                              hipStream_t stream)
{
    const float* hs   = (const float*)d_in[0];   // [4,1024,1024]
    const float* qkvw = (const float*)d_in[1];   // [3072,1024]
    const float* qkvb = (const float*)d_in[2];   // [3072]
    const float* demb = (const float*)d_in[3];   // [2047,64]
    const float* mask = (const float*)d_in[4];   // [4,1,1,1024]
    float* out = (float*)d_out;

    char* ws = (char*)d_ws;
    unsigned short* hsb = (unsigned short*)(ws);              // 8,388,608 B
    unsigned short* Wb  = (unsigned short*)(ws + 8388608);    // 6,291,456 B
    unsigned short* Eb  = (unsigned short*)(ws + 14680064);   //   262,016 B
    unsigned short* Qb  = (unsigned short*)(ws + 14942208);   // 8,388,608 B (pre-scaled)
    unsigned short* Kb  = (unsigned short*)(ws + 23330816);   // 8,388,608 B
    unsigned short* Vt  = (unsigned short*)(ws + 31719424);   // 8,388,608 B (transposed)
    float* pOx = (float*)(ws + 40108032);                     // extra partials start here

    // np=3: pOx 2x16,777,216 -> end 73,662,464; m 786,432 -> 74,448,896; l 786,432 -> 75,235,328
    // np=2 fallback (R16-proven footprint): pOx 16,777,216 -> 56,885,248; m/l 2x524,288 -> 57,933,824
    const int np = (ws_size >= 75235328) ? 3 : 2;
    float* mArr = (np == 3) ? (float*)(ws + 73662464) : (float*)(ws + 56885248);
    float* lArr = (np == 3) ? (float*)(ws + 74448896) : (float*)(ws + 57409536);

    cast_kernel<<<2048, 256, 0, stream>>>(hs, qkvw, demb, hsb, Wb, Eb);
    qkv_gemm<<<dim3(24, 32), 256, 0, stream>>>(hsb, Wb, qkvb, Qb, Kb, Vt);
    attn_split<<<1024 * np, 256, 0, stream>>>(Qb, Kb, Vt, Eb, mask, out, pOx, mArr, lArr, np);
    merge_kernel<<<4096, 256, 0, stream>>>(out, pOx, mArr, lArr, out, np);
}

// Round 18
// 217.595 us; speedup vs baseline: 1.0860x; 1.0860x over previous
//
#include <hip/hip_runtime.h>
#include <hip/hip_bf16.h>

#define SEQ 1024
#define NH  16

typedef __attribute__((ext_vector_type(8))) short short8;
typedef __attribute__((ext_vector_type(4))) float floatx4;
typedef __attribute__((ext_vector_type(4))) unsigned short ushortx4;

// async global->LDS, 16B per lane; LDS dest = wave-uniform base + lane*16
#define GLDS16(gp, lp) __builtin_amdgcn_global_load_lds( \
    (const __attribute__((address_space(1))) void*)(gp), \
    (__attribute__((address_space(3))) void*)(lp), 16, 0, 0)

// fp32 -> bf16 RNE via native HW convert (compiler pairs into v_cvt_pk_bf16_f32)
__device__ __forceinline__ unsigned short f2b(float f) {
    union { __hip_bfloat16 h; unsigned short u; } v;
    v.h = __float2bfloat16(f);
    return v.u;
}
__device__ __forceinline__ float b2f(unsigned short h) {
    union { unsigned u; float f; } v; v.u = ((unsigned)h) << 16;
    return v.f;
}

// swizzled addr helper (element offsets in a 64-wide bf16 tile: 8 chunks of 16B/row)
#define TADDR(base, row, ch) ((base) + ((row) << 6) + ((((ch) ^ ((row) & 7))) << 3))

// ---------------- k0: fp32 -> bf16 casts ----------------
__global__ void cast_kernel(const float* __restrict__ hs, const float* __restrict__ W,
                            const float* __restrict__ E,
                            unsigned short* __restrict__ hsb,
                            unsigned short* __restrict__ Wb,
                            unsigned short* __restrict__ Eb)
{
    const int QH = 1048576, QW = 786432, QE = 32752;   // quads
    const int NT = QH + QW + QE;
    for (int q = blockIdx.x * 256 + threadIdx.x; q < NT; q += gridDim.x * 256) {
        const float* src; unsigned short* dst; int off;
        if (q < QH)           { src = hs; dst = hsb; off = q; }
        else if (q < QH + QW) { src = W;  dst = Wb;  off = q - QH; }
        else                  { src = E;  dst = Eb;  off = q - QH - QW; }
        const float4 v = *(const float4*)(src + (size_t)off * 4);
        ushortx4 o; o[0] = f2b(v.x); o[1] = f2b(v.y); o[2] = f2b(v.z); o[3] = f2b(v.w);
        *(ushortx4*)(dst + (size_t)off * 4) = o;
    }
}

// ---------------- k1: QKV projection — 2-phase K-loop + LDS-staged coalesced epilogue ----
// L2-blocked XCD mapping: each XCD (bid&7) owns an 8-m x 12-o chunk of the 32x24
// block grid -> per-XCD working set A 2.1MB + B 3.1MB ~ 4MB L2 (was 4m x 24o:
// B 6.3MB > L2 -> B thrashed L2 and streamed from L3 every K-step).
__global__ __launch_bounds__(256, 3) void qkv_gemm(
    const unsigned short* __restrict__ Ab, const unsigned short* __restrict__ Bb,
    const float* __restrict__ bias,
    unsigned short* __restrict__ Qb, unsigned short* __restrict__ Kb,
    unsigned short* __restrict__ Vt)
{
    __shared__ unsigned short sm[16384];
    const int t = threadIdx.x, w = t >> 6;
    const int ln = t & 15, g = (t >> 4) & 3;
    const int wm = w >> 1, wn = w & 1;
    const int bid = blockIdx.x + blockIdx.y * 24;
    const int xcd = bid & 7, local = bid >> 3;   // local in [0,96)
    const int mi_ = local & 7, oi_ = local >> 3; // 8 m-rows x 12 o-cols per XCD
    const int m0 = (((xcd & 3) << 3) + mi_) << 7;
    const int o0 = ((xcd >> 2) * 12 + oi_) << 7;

    floatx4 acc[4][4];
#pragma unroll
    for (int i = 0; i < 4; ++i)
#pragma unroll
        for (int j = 0; j < 4; ++j) acc[i][j] = (floatx4){0.f, 0.f, 0.f, 0.f};

    auto stage = [&](int kb, int buf) {
        const int base = buf << 14;              // bytes
#pragma unroll
        for (int p = 0; p < 2; ++p) {
            const int idx = (p << 8) + t;
            const int row = idx >> 2;
            const int c = (idx & 3) ^ ((row ^ (row >> 2)) & 3);
            GLDS16(Ab + (size_t)(m0 + row) * 1024 + kb + (c << 3),
                   (char*)sm + base + (p << 12) + (w << 10));
            GLDS16(Bb + (size_t)(o0 + row) * 1024 + kb + (c << 3),
                   (char*)sm + base + 8192 + (p << 12) + (w << 10));
        }
    };

    stage(0, 0);
    __syncthreads();
    int buf = 0;
    for (int kb = 0; kb < 1024; kb += 32) {
        if (kb + 32 < 1024) stage(kb + 32, buf ^ 1);   // issue next-tile loads early
        const int be = buf << 13;                      // elems
        short8 af[4], bf_[4];
#pragma unroll
        for (int i = 0; i < 4; ++i) {
            const int r = (wm << 6) + (i << 4) + ln;
            af[i] = *(const short8*)&sm[be + (r << 5) + ((g ^ ((r ^ (r >> 2)) & 3)) << 3)];
        }
#pragma unroll
        for (int j = 0; j < 4; ++j) {
            const int r = (wn << 6) + (j << 4) + ln;
            bf_[j] = *(const short8*)&sm[be + 4096 + (r << 5) + ((g ^ ((r ^ (r >> 2)) & 3)) << 3)];
        }
#pragma unroll
        for (int i = 0; i < 4; ++i)
#pragma unroll
            for (int j = 0; j < 4; ++j)
                acc[i][j] = __builtin_amdgcn_mfma_f32_16x16x32_bf16(af[i], bf_[j], acc[i][j], 0, 0, 0);
        __syncthreads();                               // drains GLDS + syncs reads
        buf ^= 1;
    }

    const int which = o0 >> 10;     // 0=Q 1=K 2=V (block-uniform)
    float bj[4];
#pragma unroll
    for (int j = 0; j < 4; ++j) bj[j] = bias[o0 + (wn << 6) + (j << 4) + ln];
    const int b0 = m0 >> 10;        // tile stays within one batch (128 | 1024)

    if (which == 2) {
        // V: LDS transposed tile, elem(oi,mi) = oi*128 + ((mi>>3)^(oi&15))*8 + (mi&7)
#pragma unroll
        for (int i = 0; i < 4; ++i)
#pragma unroll
            for (int j = 0; j < 4; ++j) {
                const int oi = (wn << 6) + (j << 4) + ln;
                const int sb = oi & 15;
#pragma unroll
                for (int q = 0; q < 4; ++q) {
                    const int mi = (wm << 6) + (i << 4) + (g << 2) + q;
                    sm[(oi << 7) + ((((mi >> 3) ^ sb)) << 3) + (mi & 7)] =
                        f2b(acc[i][j][q] + bj[j]);
                }
            }
        __syncthreads();
#pragma unroll
        for (int it = 0; it < 8; ++it) {
            const int c = (it << 8) + t;
            const int oi = c >> 4, mi0 = (c & 15) << 3;
            const short8 v = *(const short8*)&sm[(oi << 7) + ((((mi0 >> 3) ^ (oi & 15))) << 3)];
            const int hh = ((o0 >> 6) + (oi >> 6)) & 15;
            const int d = oi & 63;
            const int s0 = (m0 & 1023) + mi0;
            *(short8*)(Vt + (((size_t)((b0 << 4) + hh)) << 16) + (d << 10) + s0) = v;
        }
    } else {
        unsigned short* dst = which ? Kb : Qb;
        const float sc = which ? 1.0f : 0.125f;   // fold 1/sqrt(64) into Q
        // Q/K: LDS row-major tile, elem(mi,oi) = mi*128 + oi
#pragma unroll
        for (int i = 0; i < 4; ++i)
#pragma unroll
            for (int j = 0; j < 4; ++j) {
                const int oi = (wn << 6) + (j << 4) + ln;
#pragma unroll
                for (int q = 0; q < 4; ++q) {
                    const int mi = (wm << 6) + (i << 4) + (g << 2) + q;
                    sm[(mi << 7) + oi] = f2b((acc[i][j][q] + bj[j]) * sc);
                }
            }
        __syncthreads();
#pragma unroll
        for (int it = 0; it < 8; ++it) {
            const int c = (it << 8) + t;
            const int mi = c >> 4, oi0 = (c & 15) << 3;
            const short8 v = *(const short8*)&sm[(mi << 7) + oi0];
            const int s = (m0 & 1023) + mi;
            const int hh = ((o0 >> 6) + (oi0 >> 6)) & 15;
            const int d0 = oi0 & 63;
            *(short8*)(dst + (((size_t)((b0 << 4) + hh)) << 16) + (s << 6) + d0) = v;
        }
    }
}

// ---------------- k2: split-K flash attention (R16-exact, np=2) ----------------
// grid 2048 = (bh, l0, half); each block runs 8 key-tiles (r0 in [half*512, half*512+512)).
// Writes UNNORMALIZED partials: O (f32) + per-row (m, l). Merge kernel combines halves.
// LDS elems (u16): K[0,4096) | E[4096,12288) (V overlays [4096,8192), P overlays [8192,12288))
//                  U'[12288,19200) 96x72 | W'[19200,25600) 64x100+1
// 50 KiB -> 3 blocks/CU.
__global__ __launch_bounds__(256, 3) void attn_split(
    const unsigned short* __restrict__ Qb, const unsigned short* __restrict__ Kb,
    const unsigned short* __restrict__ Vt, const unsigned short* __restrict__ Eb,
    const float* __restrict__ mask,
    float* __restrict__ pO0, float* __restrict__ pO1,
    float* __restrict__ mA, float* __restrict__ lA,
    float* __restrict__ mB, float* __restrict__ lB)
{
    __shared__ __align__(16) unsigned short sm[25600];
    const int t = threadIdx.x, w = t >> 6;
    const int wu = __builtin_amdgcn_readfirstlane(w);   // wave-uniform in SGPR
    const int ln = t & 15, g = (t >> 4) & 3;
    const int bid = blockIdx.x;
    const int u = ((bid & 7) << 8) + (bid >> 3);        // XCD-bijective on [0,2048)
    const int half = u & 1;
    const int rest = u >> 1;                            // [0,1024)
    const int bh = rest >> 4;
    const int l0 = (rest & 15) << 6;
    const int b = bh >> 4, h = bh & 15;
    const size_t hb = (size_t)bh << 16;
    const int x0 = (w << 4) + (g << 2);          // thread's base l-row
    const int r0beg = half << 9, r0end = (half << 9) + 512;

    // Q fragments direct from global (pre-scaled; read once, L2-hot)
    const int qr = (w << 4) + ln;
    const short8 qa0 = *(const short8*)(Qb + hb + ((size_t)(l0 + qr) << 6) + (g << 3));
    const short8 qa1 = *(const short8*)(Qb + hb + ((size_t)(l0 + qr) << 6) + 32 + (g << 3));

    floatx4 O[4];
    float mr[4], lr[4];
#pragma unroll
    for (int dt = 0; dt < 4; ++dt) O[dt] = (floatx4){0.f, 0.f, 0.f, 0.f};
#pragma unroll
    for (int q = 0; q < 4; ++q) { mr[q] = -1e30f; lr[q] = 0.f; }

    for (int r0 = r0beg; r0 < r0end; r0 += 64) {
        __syncthreads();                         // A: prev PV/V reads done
#pragma unroll
        for (int p = 0; p < 2; ++p) {            // stage K at elems [0,4096)
            const int idx = (p << 8) + t;
            const int row = idx >> 3;
            const int c = (idx & 7) ^ (row & 7);
            GLDS16(Kb + hb + ((size_t)(r0 + row) << 6) + (c << 3),
                   (char*)sm + (p << 12) + (w << 10));
        }
        const int j0 = l0 - r0 + 960;            // E band start, in [0,1920]
#pragma unroll
        for (int p = 0; p < 4; ++p) {            // stage E band (128 rows) at elems [4096,12288)
            const int idx = (p << 8) + t;
            const int row = idx >> 3;
            const int c = (idx & 7) ^ (row & 7);
            GLDS16(Eb + ((size_t)(j0 + row) << 6) + (c << 3),
                   (char*)sm + 8192 + (p << 12) + (w << 10));
        }
        __syncthreads();                         // B: staging visible
        short8 kf[4][2];
#pragma unroll
        for (int j = 0; j < 4; ++j) {
            const int kr = (j << 4) + ln;
            kf[j][0] = *(const short8*)&sm[TADDR(0, kr, g)];
            kf[j][1] = *(const short8*)&sm[TADDR(0, kr, 4 + g)];
        }
        const int wr = (w << 4) + ln;            // W A-fragment (this wave's K rows)
        const short8 ka0 = *(const short8*)&sm[TADDR(0, wr, g)];
        const short8 ka1 = *(const short8*)&sm[TADDR(0, wr, 4 + g)];

        floatx4 S[4];
#pragma unroll
        for (int j = 0; j < 4; ++j) {
            floatx4 z = (floatx4){0.f, 0.f, 0.f, 0.f};
            z = __builtin_amdgcn_mfma_f32_16x16x32_bf16(qa0, kf[j][0], z, 0, 0, 0);
            S[j] = __builtin_amdgcn_mfma_f32_16x16x32_bf16(qa1, kf[j][1], z, 0, 0, 0);
        }
        // band GEMMs, pruned per wave; outputs written pre-sheared
#pragma unroll
        for (int dt = 0; dt < 8; ++dt) {
            const bool doU = (dt >= wu) && (dt <= wu + 4);
            const bool doW = (dt >= 3 - wu) && (dt <= 7 - wu);
            if (!doU && !doW) continue;
            const int er = (dt << 4) + ln;
            const short8 e0 = *(const short8*)&sm[TADDR(4096, er, g)];
            const short8 e1 = *(const short8*)&sm[TADDR(4096, er, 4 + g)];
            if (doU) {
                floatx4 z = (floatx4){0.f, 0.f, 0.f, 0.f};
                z = __builtin_amdgcn_mfma_f32_16x16x32_bf16(qa0, e0, z, 0, 0, 0);
                const floatx4 U = __builtin_amdgcn_mfma_f32_16x16x32_bf16(qa1, e1, z, 0, 0, 0);
                // cell (rr = ll-br+63, ll), ll = x0+q, br = 16dt+ln; rr+16 in [0,95]
                int a = 12288 + (x0 - (dt << 4) - ln + 79) * 72 + x0;
#pragma unroll
                for (int q = 0; q < 4; ++q) { sm[a] = f2b(U[q]); a += 73; }
            }
            if (doW) {
                floatx4 z2 = (floatx4){0.f, 0.f, 0.f, 0.f};
                z2 = __builtin_amdgcn_mfma_f32_16x16x32_bf16(ka0, e0, z2, 0, 0, 0);
                const floatx4 Wv = __builtin_amdgcn_mfma_f32_16x16x32_bf16(ka1, e1, z2, 0, 0, 0);
                // cell (rW = x0+q, ll+16 = 16dt+ln+x0+q-47), ll+16 in [1,95]
                int a = 19200 + x0 * 101 + (dt << 4) + ln - 47;
#pragma unroll
                for (int q = 0; q < 4; ++q) { sm[a] = f2b(Wv[q] * 0.125f); a += 101; }
            }
        }
        __syncthreads();                         // C: U'/W' visible; E dead
#pragma unroll
        for (int p = 0; p < 2; ++p) {            // stage V (transposed) over dead E
            const int idx = (p << 8) + t;
            const int row = idx >> 3;            // = d
            const int c = (idx & 7) ^ (row & 7);
            GLDS16(Vt + hb + ((size_t)row << 10) + r0 + (c << 3),
                   (char*)sm + 8192 + (p << 12) + (w << 10));
        }
        // assemble scores: vector b64 reads + global mask (L2-hot)
        float Pw[4][4];
#pragma unroll
        for (int j = 0; j < 4; ++j) {
            const int rr = (j << 4) + ln;
            const float mk = mask[(b << 10) + r0 + rr];
            const ushortx4 u4 = *(const ushortx4*)&sm[12288 + (rr + 16) * 72 + x0];
            const ushortx4 w4 = *(const ushortx4*)&sm[19200 + rr * 100 + 16 + x0];
#pragma unroll
            for (int q = 0; q < 4; ++q)
                S[j][q] += b2f(u4[q]) + b2f(w4[q]) + mk;
        }
#pragma unroll
        for (int q = 0; q < 4; ++q) {
            float tm = fmaxf(fmaxf(S[0][q], S[1][q]), fmaxf(S[2][q], S[3][q]));
            tm = fmaxf(tm, __shfl_xor(tm, 1));
            tm = fmaxf(tm, __shfl_xor(tm, 2));
            tm = fmaxf(tm, __shfl_xor(tm, 4));
            tm = fmaxf(tm, __shfl_xor(tm, 8));
            const float mnew = fmaxf(mr[q], tm);
            const float al = __expf(mr[q] - mnew);
            float sum = 0.f;
#pragma unroll
            for (int j = 0; j < 4; ++j) {
                const float p = __expf(S[j][q] - mnew);
                Pw[j][q] = p; sum += p;
            }
            sum += __shfl_xor(sum, 1);
            sum += __shfl_xor(sum, 2);
            sum += __shfl_xor(sum, 4);
            sum += __shfl_xor(sum, 8);
            lr[q] = lr[q] * al + sum;
            mr[q] = mnew;
#pragma unroll
            for (int dt = 0; dt < 4; ++dt) O[dt][q] *= al;
        }
        // write P (bf16) into [l][r] swizzled tile at elem 8192
#pragma unroll
        for (int j = 0; j < 4; ++j) {
            const int rr = (j << 4) + ln;
#pragma unroll
            for (int q = 0; q < 4; ++q) {
                const int l = x0 + q;
                sm[8192 + (l << 6) + ((((rr >> 3) ^ (l & 7)) << 3)) + (rr & 7)] = f2b(Pw[j][q]);
            }
        }
        __syncthreads();                         // D: P + V visible
        const int pr = (w << 4) + ln;
        const short8 pa0 = *(const short8*)&sm[TADDR(8192, pr, g)];
        const short8 pa1 = *(const short8*)&sm[TADDR(8192, pr, 4 + g)];
#pragma unroll
        for (int dt = 0; dt < 4; ++dt) {
            const int vr = (dt << 4) + ln;       // = d row of V^T tile
            const short8 v0 = *(const short8*)&sm[TADDR(4096, vr, g)];
            const short8 v1 = *(const short8*)&sm[TADDR(4096, vr, 4 + g)];
            O[dt] = __builtin_amdgcn_mfma_f32_16x16x32_bf16(pa0, v0, O[dt], 0, 0, 0);
            O[dt] = __builtin_amdgcn_mfma_f32_16x16x32_bf16(pa1, v1, O[dt], 0, 0, 0);
        }
    }
    // write UNNORMALIZED partial O + per-row (m, l)
    float* pDst = half ? pO1 : pO0;
    float* mDst = half ? mB : mA;
    float* lDst = half ? lB : lA;
#pragma unroll
    for (int dt = 0; dt < 4; ++dt)
#pragma unroll
        for (int q = 0; q < 4; ++q) {
            const int l = x0 + q;
            pDst[((size_t)b << 20) + ((size_t)(l0 + l) << 10) + (h << 6) + (dt << 4) + ln]
                = O[dt][q];
        }
    if (ln == 0) {
        const int rowbase = (bh << 10) + l0 + x0;
#pragma unroll
        for (int q = 0; q < 4; ++q) { mDst[rowbase + q] = mr[q]; lDst[rowbase + q] = lr[q]; }
    }
}

// ---------------- k3: merge the two split-K halves ----------------
__global__ void merge_kernel(const float* __restrict__ pO0, const float* __restrict__ pO1,
                             const float* __restrict__ mA, const float* __restrict__ lA,
                             const float* __restrict__ mB, const float* __restrict__ lB,
                             float* __restrict__ outp)
{
    const int idx = blockIdx.x * 256 + threadIdx.x;      // 1,048,576 threads
    const int rowg = idx >> 4, d4 = (idx & 15) << 2;
    const int b = rowg >> 14, h = (rowg >> 10) & 15, l = rowg & 1023;
    const size_t off = ((size_t)b << 20) + ((size_t)l << 10) + (h << 6) + d4;
    const float m1 = mA[rowg], m2 = mB[rowg];
    const float mm = fmaxf(m1, m2);
    const float a1 = __expf(m1 - mm), a2 = __expf(m2 - mm);
    const float inv = 1.f / (a1 * lA[rowg] + a2 * lB[rowg]);
    const float4 o1 = *(const float4*)(pO0 + off);
    const float4 o2 = *(const float4*)(pO1 + off);
    float4 r;
    r.x = (a1 * o1.x + a2 * o2.x) * inv;
    r.y = (a1 * o1.y + a2 * o2.y) * inv;
    r.z = (a1 * o1.z + a2 * o2.z) * inv;
    r.w = (a1 * o1.w + a2 * o2.w) * inv;
    *(float4*)(outp + off) = r;
}

extern "C" void kernel_launch(void* const* d_in, const int* in_sizes, int n_in,
                              void* d_out, int out_size, void* d_ws, size_t ws_size,
                              hipStream_t stream)
{
    const float* hs   = (const float*)d_in[0];   // [4,1024,1024]
    const float* qkvw = (const float*)d_in[1];   // [3072,1024]
    const float* qkvb = (const float*)d_in[2];   // [3072]
    const float* demb = (const float*)d_in[3];   // [2047,64]
    const float* mask = (const float*)d_in[4];   // [4,1,1,1024]
    float* out = (float*)d_out;

    char* ws = (char*)d_ws;
    unsigned short* hsb = (unsigned short*)(ws);              // 8,388,608 B
    unsigned short* Wb  = (unsigned short*)(ws + 8388608);    // 6,291,456 B
    unsigned short* Eb  = (unsigned short*)(ws + 14680064);   //   262,016 B
    unsigned short* Qb  = (unsigned short*)(ws + 14942208);   // 8,388,608 B (pre-scaled)
    unsigned short* Kb  = (unsigned short*)(ws + 23330816);   // 8,388,608 B
    unsigned short* Vt  = (unsigned short*)(ws + 31719424);   // 8,388,608 B (transposed)
    float* pO1 = (float*)(ws + 40108032);                     // 16,777,216 B (half-1 partial O)
    float* mA  = (float*)(ws + 56885248);                     // 262,144 B
    float* lA  = (float*)(ws + 57147392);                     // 262,144 B
    float* mB  = (float*)(ws + 57409536);                     // 262,144 B
    float* lB  = (float*)(ws + 57671680);                     // 262,144 B  (end 57,933,824)

    cast_kernel<<<2048, 256, 0, stream>>>(hs, qkvw, demb, hsb, Wb, Eb);
    qkv_gemm<<<dim3(24, 32), 256, 0, stream>>>(hsb, Wb, qkvb, Qb, Kb, Vt);
    attn_split<<<2048, 256, 0, stream>>>(Qb, Kb, Vt, Eb, mask, out, pO1, mA, lA, mB, lB);
    merge_kernel<<<4096, 256, 0, stream>>>(out, pO1, mA, lA, mB, lB, out);
}